// Round 2
// baseline (26175.308 us; speedup 1.0000x reference)
//
#include <hip/hip_runtime.h>
#include <hip/hip_cooperative_groups.h>
#include <stdint.h>
#include <string.h>

namespace cg = cooperative_groups;

#define NBATCH 8
#define NSPK_  4
#define DIMS   512
#define TLEN   2000
#define KC     4
#define NPTS   (NSPK_*TLEN)    // 8000 points per batch
#define TILE   250             // t-columns per block unit (2000/8)
#define NBLK   256             // 8b * 4n * 8 t-chunks
#define NTHR   256
#define MAXIT  100
#define DCH    64              // d rows per LDS chunk
#define XH     125             // t half-tile staged at a time
#define XSTR   129             // LDS row stride (odd -> conflict-free column reads)

// Use JAX >= 0.4.30 default (jax_threefry_partitionable = True)
#define THREEFRY_PARTITIONABLE 1

struct RArg { float r[3][NBATCH]; };

__device__ __forceinline__ float wredf(float v){
  #pragma unroll
  for (int o = 32; o; o >>= 1) v += __shfl_xor(v, o, 64);
  return v;
}

// ---- exact replica of numpy pairwise_sum (umath loops), stride in elements ----
__device__ float np_pw(const float* a, int n, int st){
  #pragma clang fp contract(off)
  if (n < 8){
    float r = 0.f;
    for (int i = 0; i < n; ++i) r += a[(long)i*st];
    return r;
  }
  if (n <= 128){
    float r0=a[0], r1=a[st], r2=a[2*st], r3=a[3*st],
          r4=a[4*st], r5=a[5*st], r6=a[6*st], r7=a[7*st];
    int i = 8;
    for (; i < n - (n & 7); i += 8){
      r0 += a[(long)(i+0)*st]; r1 += a[(long)(i+1)*st];
      r2 += a[(long)(i+2)*st]; r3 += a[(long)(i+3)*st];
      r4 += a[(long)(i+4)*st]; r5 += a[(long)(i+5)*st];
      r6 += a[(long)(i+6)*st]; r7 += a[(long)(i+7)*st];
    }
    float res = ((r0 + r1) + (r2 + r3)) + ((r4 + r5) + (r6 + r7));
    for (; i < n; ++i) res += a[(long)i*st];
    return res;
  }
  int n2 = n/2; n2 -= (n2 & 7);
  return np_pw(a, n2, st) + np_pw(a + (long)n2*st, n - n2, st);
}
// pairwise sum of squares: identical order; each square rounds separately
// (contract off) exactly like numpy's materialized flat**2 then pairwise sum.
__device__ float np_pw_sq(const float* a, int n, int st){
  #pragma clang fp contract(off)
  if (n < 8){
    float r = 0.f;
    for (int i = 0; i < n; ++i){ float x = a[(long)i*st]; float s = x*x; r += s; }
    return r;
  }
  if (n <= 128){
    float x0=a[0],x1=a[st],x2=a[2*st],x3=a[3*st],
          x4=a[4*st],x5=a[5*st],x6=a[6*st],x7=a[7*st];
    float r0=x0*x0, r1=x1*x1, r2=x2*x2, r3=x3*x3,
          r4=x4*x4, r5=x5*x5, r6=x6*x6, r7=x7*x7;
    int i = 8;
    for (; i < n - (n & 7); i += 8){
      float y0=a[(long)(i+0)*st], y1=a[(long)(i+1)*st], y2=a[(long)(i+2)*st], y3=a[(long)(i+3)*st];
      float y4=a[(long)(i+4)*st], y5=a[(long)(i+5)*st], y6=a[(long)(i+6)*st], y7=a[(long)(i+7)*st];
      r0 += y0*y0; r1 += y1*y1; r2 += y2*y2; r3 += y3*y3;
      r4 += y4*y4; r5 += y5*y5; r6 += y6*y6; r7 += y7*y7;
    }
    float res = ((r0 + r1) + (r2 + r3)) + ((r4 + r5) + (r6 + r7));
    for (; i < n; ++i){ float x = a[(long)i*st]; float s = x*x; res += s; }
    return res;
  }
  int n2 = n/2; n2 -= (n2 & 7);
  return np_pw_sq(a, n2, st) + np_pw_sq(a + (long)n2*st, n - n2, st);
}

__global__ __launch_bounds__(NTHR, 1)
void kmeans_all(const float* __restrict__ X, float* __restrict__ centers,
                float* __restrict__ fsq, float* __restrict__ dmin,
                unsigned* __restrict__ idxg, float* __restrict__ part,
                int* __restrict__ partnum, float* __restrict__ csumg,
                int* __restrict__ flagg, RArg ra)
{
  cg::grid_group grid = cg::this_grid();
  const int blk = blockIdx.x, tid = threadIdx.x;
  const int lane = tid & 63, wv = tid >> 6;
  const int ub = blk >> 5;            // batch
  const int un = (blk >> 3) & 3;      // speaker
  const int uc = blk & 7;             // t-chunk
  const int t0 = uc * TILE;
  const int rowbase = ((ub*NSPK_ + un)*DIMS)*TLEN + t0;  // (b,n,0,t0)
  const int ptbase  = ub*NPTS + un*TLEN + t0;            // flat point index base

  __shared__ __align__(16) float cent[DIMS][KC];   // centers, d-major
  __shared__ float xch[DCH][XSTR];                 // staged x tile
  __shared__ float sums4[4][KC][DCH];              // per-wave partial sums
  __shared__ float dbuf[NPTS];                     // selection: per-batch dmin copy
  __shared__ unsigned idxs[NTHR];
  __shared__ float csq_s[KC];
  __shared__ double red[4];
  __shared__ int cnt_s[KC];
  __shared__ int blkchg;
  __shared__ int sel_sh;
  __shared__ int stop_sh;
  __shared__ float tot_sh;

  // ---------------- stage 0: flags, zero rows 1..3, row 0, fsq (np-pairwise)
  if (blk == 0) for (int i = tid; i < MAXIT; i += NTHR) flagg[i] = 0;
  { int gid = blk*NTHR + tid;
    if (gid < NBATCH*3*DIMS){
      int b = gid / (3*DIMS); int rem = gid - b*3*DIMS;
      centers[b*KC*DIMS + DIMS + rem] = 0.f;   // rows 1..3 = 0
    } }
  if (un == 0 && uc == 0){
    for (int d = tid; d < DIMS; d += NTHR)
      centers[ub*KC*DIMS + d] = X[((ub*NSPK_ + 0)*DIMS + d)*TLEN + 0];  // feature[:,0,:,0]
  }
  if (tid < TILE){
    fsq[ptbase + tid] = np_pw_sq(X + rowbase + tid, DIMS, TLEN);
  }
  grid.sync();

  // ---------------- kmeans++ init (i = 1..3)
  for (int i = 1; i < KC; ++i){
    // sum(c^2) per (b,k): np-pairwise exact (contiguous rows)
    if (blk < NBATCH*KC && tid == 0){
      int b = blk >> 2, k = blk & 3;
      csumg[b*KC + k] = np_pw_sq(centers + (b*KC + k)*DIMS, DIMS, 1);
    }
    grid.sync();

    // dmin over k = 0..i  (row i still zero -> dist_i = fsq, as in reference)
    for (int j = tid; j < KC*DIMS; j += NTHR)
      cent[j & (DIMS-1)][j >> 9] = centers[ub*KC*DIMS + j];
    if (tid < KC) csq_s[tid] = csumg[ub*KC + tid];
    __syncthreads();
    if (tid < TILE){
      const float* p = X + rowbase + tid;
      float a0=0,a1=0,a2=0,a3=0;
      #pragma unroll 4
      for (int d = 0; d < DIMS; ++d){
        float x = p[d*TLEN];
        float4 c4 = *(const float4*)(&cent[d][0]);
        a0 += x*c4.x; a1 += x*c4.y; a2 += x*c4.z; a3 += x*c4.w;
      }
      float fs = fsq[ptbase + tid];
      float dm = (fs + csq_s[0]) - 2.f*a0;
      { float dk = (fs + csq_s[1]) - 2.f*a1; dm = fminf(dm, dk); }
      if (i >= 2){ float dk = (fs + csq_s[2]) - 2.f*a2; dm = fminf(dm, dk); }
      if (i >= 3){ float dk = (fs + csq_s[3]) - 2.f*a3; dm = fminf(dm, dk); }
      dmin[ptbase + tid] = dm;
    }
    grid.sync();

    // weighted selection: blocks 0..7, np-exact (pairwise total, sequential fp32 cumsum)
    if (blk < NBATCH){
      int b = blk;
      for (int j = tid; j < NPTS; j += NTHR) dbuf[j] = dmin[b*NPTS + j];
      __syncthreads();
      if (tid == 0) tot_sh = np_pw(dbuf, NPTS, 1);
      __syncthreads();
      { float tt = tot_sh;
        for (int j = tid; j < NPTS; j += NTHR) dbuf[j] = dbuf[j] / tt; }
      __syncthreads();
      if (tid == 0){
        #pragma clang fp contract(off)
        float run = 0.f; int cnt = 0;
        float rT = ra.r[i-1][b];
        for (int j = 0; j < NPTS; ++j){
          run = run + dbuf[j];          // np.cumsum: sequential fp32
          if (run <= rT) ++cnt;
        }
        sel_sh = cnt - 1;
      }
      __syncthreads();
      int sel = sel_sh;
      for (int d = tid; d < DIMS; d += NTHR){
        float v = 0.f;
        if (sel >= 0){
          int ns = sel / TLEN, ts = sel - ns*TLEN;
          v = X[((b*NSPK_ + ns)*DIMS + d)*TLEN + ts];
        }
        centers[(b*KC + i)*DIMS + d] = v;
      }
    }
    grid.sync();
  }

  // ---------------- csq for the Lloyd loop
  if (blk < NBATCH*KC){
    int b = blk >> 2, k = blk & 3;
    float a = 0.f;
    for (int d = tid; d < DIMS; d += NTHR){ float c = centers[(b*KC+k)*DIMS + d]; a += c*c; }
    a = wredf(a);
    if (lane == 0) red[wv] = (double)a;
    __syncthreads();
    if (tid == 0) csumg[b*KC+k] = (float)(red[0]+red[1]+red[2]+red[3]);
  }
  grid.sync();

  // ---------------- 100 Lloyd iterations with exact early exit
  const int tb = (XH*wv) >> 2, te = (XH*(wv+1)) >> 2;   // quarter of the 125 half-tile
  for (int it = 0; it < MAXIT; ++it){
    if (it > 0){
      if (tid == 0) stop_sh = atomicAdd(&flagg[it-1], 0);
      __syncthreads();
      if (stop_sh == 0) break;  // assignments stable -> centers bitwise fixed
    }

    // --- pass A: assignment
    for (int j = tid; j < KC*DIMS; j += NTHR)
      cent[j & (DIMS-1)][j >> 9] = centers[ub*KC*DIMS + j];
    if (tid < KC){ csq_s[tid] = csumg[ub*KC + tid] * (1.f/512.f); cnt_s[tid] = 0; }
    if (tid == 0) blkchg = 0;
    __syncthreads();
    unsigned myidx = 0; int changed = 0;
    if (tid < TILE){
      const float* p = X + rowbase + tid;
      float a0=0,a1=0,a2=0,a3=0;
      #pragma unroll 4
      for (int d = 0; d < DIMS; ++d){
        float x = p[d*TLEN];
        float4 c4 = *(const float4*)(&cent[d][0]);
        a0 += x*c4.x; a1 += x*c4.y; a2 += x*c4.z; a3 += x*c4.w;
      }
      float xs = fsq[ptbase + tid] * (1.f/512.f);
      float d0 = (xs + csq_s[0]) - 2.f*(a0*(1.f/512.f));
      float d1 = (xs + csq_s[1]) - 2.f*(a1*(1.f/512.f));
      float d2 = (xs + csq_s[2]) - 2.f*(a2*(1.f/512.f));
      float d3 = (xs + csq_s[3]) - 2.f*(a3*(1.f/512.f));
      unsigned bi = 0; float bv = d0;               // first-min == np.argmin
      if (d1 < bv){ bv = d1; bi = 1; }
      if (d2 < bv){ bv = d2; bi = 2; }
      if (d3 < bv){ bv = d3; bi = 3; }
      myidx = bi;
      unsigned prev = idxg[ptbase + tid];
      changed = (it == 0) || (prev != bi);
      idxg[ptbase + tid] = bi;
    }
    idxs[tid] = myidx;
    __syncthreads();
    if (tid < TILE){
      atomicAdd(&cnt_s[myidx], 1);
      if (changed) blkchg = 1;
    }
    __syncthreads();
    if (tid == 0 && blkchg) atomicOr(&flagg[it], 1);
    if (tid < KC) partnum[blk*KC + tid] = cnt_s[tid];

    // --- pass B: per-cluster sums (LDS column tiles, deterministic order)
    for (int dc = 0; dc < DIMS; dc += DCH){
      float a0=0,a1=0,a2=0,a3=0;
      for (int h = 0; h < 2; ++h){
        int tH = h * XH;
        __syncthreads();  // xch free
        for (int r = wv; r < DCH; r += 4){
          const float* src = X + ((ub*NSPK_ + un)*DIMS + dc + r)*TLEN + t0 + tH;
          float* dst = &xch[r][0];
          for (int off = lane; off < XH; off += 64) dst[off] = src[off];
        }
        __syncthreads();
        for (int tt = tb; tt < te; ++tt){           // lane <-> d, t wave-uniform
          float x = xch[lane][tt];
          int k = __builtin_amdgcn_readfirstlane((int)idxs[tH + tt]);
          if (k == 0) a0 += x; else if (k == 1) a1 += x;
          else if (k == 2) a2 += x; else a3 += x;
        }
      }
      sums4[wv][0][lane] = a0; sums4[wv][1][lane] = a1;
      sums4[wv][2][lane] = a2; sums4[wv][3][lane] = a3;
      __syncthreads();
      { int k = tid >> 6, l = lane;                  // fixed-order wave combine
        float s = sums4[0][k][l] + sums4[1][k][l] + sums4[2][k][l] + sums4[3][k][l];
        part[(blk*KC + k)*DIMS + dc + l] = s; }
    }
    grid.sync();

    // --- phase 3: reduce partials -> centers, csq (fixed order -> deterministic)
    if (blk < NBATCH*KC){
      int b = blk >> 2, k = blk & 3;
      int num = 0;
      #pragma unroll 4
      for (int j = 0; j < 32; ++j) num += partnum[(b*32 + j)*KC + k];
      float den = (float)num + 1e-8f;
      float a = 0.f;
      for (int d = tid; d < DIMS; d += NTHR){
        float s = 0.f;
        #pragma unroll 4
        for (int j = 0; j < 32; ++j) s += part[((b*32 + j)*KC + k)*DIMS + d];
        float c = s / den;
        centers[(b*KC + k)*DIMS + d] = c;
        a += c*c;
      }
      a = wredf(a);
      if (lane == 0) red[wv] = (double)a;
      __syncthreads();
      if (tid == 0) csumg[b*KC + k] = (float)(red[0]+red[1]+red[2]+red[3]);
    }
    grid.sync();
  }
}

// ======================= host: threefry2x32 (JAX-compatible) =======================
static inline uint32_t rotl_(uint32_t x, int r){ return (x << r) | (x >> (32 - r)); }
static void tf2x32(uint32_t k0, uint32_t k1, uint32_t x0, uint32_t x1,
                   uint32_t* o0, uint32_t* o1){
  static const int R0[4] = {13,15,26,6}, R1[4] = {17,29,16,24};
  uint32_t ks[3] = { k0, k1, k0 ^ k1 ^ 0x1BD11BDAu };
  x0 += ks[0]; x1 += ks[1];
  for (int g = 0; g < 5; ++g){
    const int* rot = (g & 1) ? R1 : R0;
    for (int r = 0; r < 4; ++r){ x0 += x1; x1 = rotl_(x1, rot[r]); x1 ^= x0; }
    x0 += ks[(g+1)%3];
    x1 += ks[(g+2)%3] + (uint32_t)(g+1);
  }
  *o0 = x0; *o1 = x1;
}
static float tf_uniform_bits(uint32_t bits){
  uint32_t u = (bits >> 9) | 0x3f800000u;
  float f; memcpy(&f, &u, 4);
  return f - 1.0f;
}

extern "C" void kernel_launch(void* const* d_in, const int* in_sizes, int n_in,
                              void* d_out, int out_size, void* d_ws, size_t ws_size,
                              hipStream_t stream) {
  (void)in_sizes; (void)n_in; (void)out_size; (void)ws_size;
  const float* X = (const float*)d_in[0];
  float* centers = (float*)d_out;                 // (8,4,512)

  char* w = (char*)d_ws;
  float*    fsq     = (float*)w;    w += (size_t)NBATCH*NPTS*4;
  float*    dminb   = (float*)w;    w += (size_t)NBATCH*NPTS*4;
  unsigned* idxgb   = (unsigned*)w; w += (size_t)NBATCH*NPTS*4;
  float*    partb   = (float*)w;    w += (size_t)NBLK*KC*DIMS*4;
  int*      partnum = (int*)w;      w += (size_t)NBLK*KC*4;
  float*    csumg   = (float*)w;    w += 128;
  int*      flagg   = (int*)w;      w += 512;

  // jax.random.key(1) -> (0,1); three rounds of (split, uniform(8,))
  RArg ra;
  uint32_t k0 = 0u, k1 = 1u;
  for (int i = 0; i < 3; ++i){
#if THREEFRY_PARTITIONABLE
    uint32_t nk0, nk1, s0, s1;
    tf2x32(k0, k1, 0u, 0u, &nk0, &nk1);           // keys[0]
    tf2x32(k0, k1, 0u, 1u, &s0, &s1);             // keys[1] = sub
    k0 = nk0; k1 = nk1;
    for (int b = 0; b < NBATCH; ++b){
      uint32_t b1v, b2v; tf2x32(s0, s1, 0u, (uint32_t)b, &b1v, &b2v);
      ra.r[i][b] = tf_uniform_bits(b1v ^ b2v);    // random_bits(32) = bits1 ^ bits2
    }
#else
    uint32_t a0, b0, a1, b1;
    tf2x32(k0, k1, 0u, 2u, &a0, &b0);
    tf2x32(k0, k1, 1u, 3u, &a1, &b1);
    uint32_t s0 = b0, s1 = b1;
    k0 = a0; k1 = a1;
    uint32_t bits[8];
    for (int j = 0; j < 4; ++j){
      uint32_t c, d2; tf2x32(s0, s1, (uint32_t)j, (uint32_t)(j+4), &c, &d2);
      bits[j] = c; bits[j+4] = d2;
    }
    for (int b = 0; b < NBATCH; ++b) ra.r[i][b] = tf_uniform_bits(bits[b]);
#endif
  }

  void* args[] = { (void*)&X, (void*)&centers, (void*)&fsq, (void*)&dminb,
                   (void*)&idxgb, (void*)&partb, (void*)&partnum, (void*)&csumg,
                   (void*)&flagg, (void*)&ra };
  hipLaunchCooperativeKernel((void*)kmeans_all, dim3(NBLK), dim3(NTHR), args, 0, stream);
}

// Round 4
// 7033.080 us; speedup vs baseline: 3.7217x; 3.7217x over previous
//
#include <hip/hip_runtime.h>
#include <stdint.h>
#include <string.h>

#define NBATCH 8
#define NSPK_  4
#define DIMS   512
#define TLEN   2000
#define KC     4
#define NPTS   8000            // points per batch
#define NBLK   1000            // Lloyd / dist grid
#define NTHR   256
#define PPB    64              // points per block
#define BPB    125             // blocks per batch
#define MAXIT  100
#define TP     65              // padded LDS tile row stride

#define THREEFRY_PARTITIONABLE 1

struct RArg { float r[3][NBATCH]; };

// ---- exact replica of numpy pairwise_sum (umath loops), stride in elements ----
__device__ float np_pw(const float* a, int n, int st){
  #pragma clang fp contract(off)
  if (n < 8){
    float r = 0.f;
    for (int i = 0; i < n; ++i) r += a[(long)i*st];
    return r;
  }
  if (n <= 128){
    float r0=a[0], r1=a[st], r2=a[2*st], r3=a[3*st],
          r4=a[4*st], r5=a[5*st], r6=a[6*st], r7=a[7*st];
    int i = 8;
    for (; i < n - (n & 7); i += 8){
      r0 += a[(long)(i+0)*st]; r1 += a[(long)(i+1)*st];
      r2 += a[(long)(i+2)*st]; r3 += a[(long)(i+3)*st];
      r4 += a[(long)(i+4)*st]; r5 += a[(long)(i+5)*st];
      r6 += a[(long)(i+6)*st]; r7 += a[(long)(i+7)*st];
    }
    float res = ((r0 + r1) + (r2 + r3)) + ((r4 + r5) + (r6 + r7));
    for (; i < n; ++i) res += a[(long)i*st];
    return res;
  }
  int n2 = n/2; n2 -= (n2 & 7);
  return np_pw(a, n2, st) + np_pw(a + (long)n2*st, n - n2, st);
}
__device__ float np_pw_sq(const float* a, int n, int st){
  #pragma clang fp contract(off)
  if (n < 8){
    float r = 0.f;
    for (int i = 0; i < n; ++i){ float x = a[(long)i*st]; float s = x*x; r += s; }
    return r;
  }
  if (n <= 128){
    float x0=a[0],x1=a[st],x2=a[2*st],x3=a[3*st],
          x4=a[4*st],x5=a[5*st],x6=a[6*st],x7=a[7*st];
    float r0=x0*x0, r1=x1*x1, r2=x2*x2, r3=x3*x3,
          r4=x4*x4, r5=x5*x5, r6=x6*x6, r7=x7*x7;
    int i = 8;
    for (; i < n - (n & 7); i += 8){
      float y0=a[(long)(i+0)*st], y1=a[(long)(i+1)*st], y2=a[(long)(i+2)*st], y3=a[(long)(i+3)*st];
      float y4=a[(long)(i+4)*st], y5=a[(long)(i+5)*st], y6=a[(long)(i+6)*st], y7=a[(long)(i+7)*st];
      r0 += y0*y0; r1 += y1*y1; r2 += y2*y2; r3 += y3*y3;
      r4 += y4*y4; r5 += y5*y5; r6 += y6*y6; r7 += y7*y7;
    }
    float res = ((r0 + r1) + (r2 + r3)) + ((r4 + r5) + (r6 + r7));
    for (; i < n; ++i){ float x = a[(long)i*st]; float s = x*x; res += s; }
    return res;
  }
  int n2 = n/2; n2 -= (n2 & 7);
  return np_pw_sq(a, n2, st) + np_pw_sq(a + (long)n2*st, n - n2, st);
}

// ======== phase 0: fsq (np-exact), center row 0 = feature[:,0,:,0], rows 1..3 = 0
__global__ __launch_bounds__(NTHR)
void k_prep(const float* __restrict__ X, float* __restrict__ C, float* __restrict__ fsq){
  const int blk = blockIdx.x, tid = threadIdx.x;
  int Pf = blk*NTHR + tid;                 // 250*256 = 64000
  int bf = Pf / NPTS, gf = Pf - bf*NPTS;
  int nf = gf / TLEN, tf = gf - nf*TLEN;
  fsq[Pf] = np_pw_sq(X + ((size_t)(bf*NSPK_ + nf)*DIMS)*TLEN + tf, DIMS, TLEN);
  if (blk < NBATCH){
    for (int d = tid; d < DIMS; d += NTHR)
      C[blk*KC*DIMS + d] = X[((size_t)(blk*NSPK_)*DIMS + d)*TLEN];
  } else if (blk < 2*NBATCH){
    int bb = blk - NBATCH;
    for (int e = tid; e < 3*DIMS; e += NTHR) C[bb*KC*DIMS + DIMS + e] = 0.f;
  }
}

// ======== init dist: dmin over all 4 rows (zero rows give fsq == reference :i+1 slice)
__global__ __launch_bounds__(NTHR)
void k_dist(const float* __restrict__ X, const float* __restrict__ C,
            const float* __restrict__ fsq, float* __restrict__ dmin){
  const int blk = blockIdx.x, tid = threadIdx.x;
  const int w = tid >> 6, l = tid & 63;
  const int b = blk / BPB;
  const int P = blk*PPB + l;
  const int g = P - b*NPTS;
  const int n = g / TLEN, t = g - n*TLEN;

  __shared__ __align__(16) float cent[DIMS*KC];
  __shared__ float red[4][KC][PPB];
  __shared__ float csq_s[KC];

  const float* Cb = C + b*KC*DIMS;
  #pragma unroll
  for (int j = 0; j < 8; ++j){
    int e = tid*8 + j;
    cent[e] = Cb[(e&3)*DIMS + (e>>2)];
  }
  { const float* ck = Cb + w*DIMS + l*8;
    float s = 0.f;
    #pragma unroll
    for (int j = 0; j < 8; ++j){ float c = ck[j]; s += c*c; }
    #pragma unroll
    for (int o = 32; o; o >>= 1) s += __shfl_xor(s, o, 64);
    if (l == 0) csq_s[w] = s;
  }
  __syncthreads();

  const float* xp = X + (((size_t)(b*NSPK_ + n)*DIMS) + w*128)*TLEN + t;
  const float4* c4p = (const float4*)cent + w*128;
  float a0=0,a1=0,a2=0,a3=0;
  #pragma unroll 8
  for (int dq = 0; dq < 128; ++dq){
    float x = xp[(size_t)dq*TLEN];
    float4 c = c4p[dq];
    a0 += x*c.x; a1 += x*c.y; a2 += x*c.z; a3 += x*c.w;
  }
  red[w][0][l]=a0; red[w][1][l]=a1; red[w][2][l]=a2; red[w][3][l]=a3;
  __syncthreads();
  if (tid < PPB){
    float A0 = red[0][0][l]+red[1][0][l]+red[2][0][l]+red[3][0][l];
    float A1 = red[0][1][l]+red[1][1][l]+red[2][1][l]+red[3][1][l];
    float A2 = red[0][2][l]+red[1][2][l]+red[2][2][l]+red[3][2][l];
    float A3 = red[0][3][l]+red[1][3][l]+red[2][3][l]+red[3][3][l];
    float fs = fsq[P];
    float dm = (fs + csq_s[0]) - 2.f*A0;
    dm = fminf(dm, (fs + csq_s[1]) - 2.f*A1);
    dm = fminf(dm, (fs + csq_s[2]) - 2.f*A2);
    dm = fminf(dm, (fs + csq_s[3]) - 2.f*A3);
    dmin[P] = dm;
  }
}

// ======== selection (np-exact): grid 8, one block per batch; writes center row i
__global__ __launch_bounds__(NTHR)
void k_select(const float* __restrict__ X, float* __restrict__ C,
              const float* __restrict__ dmin, RArg ra, int i){
  const int bs = blockIdx.x, tid = threadIdx.x;
  __shared__ float sbuf[TLEN];
  __shared__ float fsh[4];
  __shared__ int   ish[1];
  float rT = ra.r[i-1][bs];

  // total = exact np pairwise tree: 8000 = ((2000+2000)+(2000+2000))
  for (int c = 0; c < 4; ++c){
    for (int e = tid; e < TLEN; e += NTHR) sbuf[e] = dmin[bs*NPTS + c*TLEN + e];
    __syncthreads();
    if (tid == 0) fsh[c] = np_pw(sbuf, TLEN, 1);
    __syncthreads();
  }
  float tot = (fsh[0] + fsh[1]) + (fsh[2] + fsh[3]);

  // q = d/tot (IEEE div, parallel) then sequential fp32 cumsum count (np semantics)
  float run = 0.f; int cnt = 0;
  for (int c = 0; c < 4; ++c){
    for (int e = tid; e < TLEN; e += NTHR) sbuf[e] = dmin[bs*NPTS + c*TLEN + e] / tot;
    __syncthreads();
    if (tid == 0){
      #pragma clang fp contract(off)
      for (int j = 0; j < TLEN; ++j){
        run = run + sbuf[j];
        if (run <= rT) ++cnt;
      }
    }
    __syncthreads();
  }
  if (tid == 0) ish[0] = cnt - 1;
  __syncthreads();
  int sel = ish[0];
  for (int d = tid; d < DIMS; d += NTHR){
    float v = 0.f;
    if (sel >= 0){
      int ns = sel / TLEN, ts = sel - ns*TLEN;
      v = X[((size_t)(bs*NSPK_ + ns)*DIMS + d)*TLEN + ts];
    }
    C[(bs*KC + i)*DIMS + d] = v;
  }
}

// ======== Lloyd iteration: fused assignment + per-block cluster sums
__global__ __launch_bounds__(NTHR, 4)
void k_iter(const float* __restrict__ X, const float* __restrict__ C,
            const float* __restrict__ fsq, float* __restrict__ part,
            int* __restrict__ pnum){
  const int blk = blockIdx.x, tid = threadIdx.x;
  const int w = tid >> 6, l = tid & 63;
  const int b = blk / BPB;
  const int P = blk*PPB + l;
  const int g = P - b*NPTS;
  const int n = g / TLEN, t = g - n*TLEN;

  __shared__ __align__(16) float cent[DIMS*KC];   // [d*4+k], 8 KB
  __shared__ float tileb[64*TP];                  // 16.6 KB
  __shared__ float red[4][KC][PPB];               // 4 KB
  __shared__ int   ks[PPB];
  __shared__ float csq_s[KC];

  // stage centers + csq (mean: scale 1/512)
  const float* Cb = C + b*KC*DIMS;
  #pragma unroll
  for (int j = 0; j < 8; ++j){
    int e = tid*8 + j;
    cent[e] = Cb[(e&3)*DIMS + (e>>2)];
  }
  { const float* ck = Cb + w*DIMS + l*8;
    float s = 0.f;
    #pragma unroll
    for (int j = 0; j < 8; ++j){ float c = ck[j]; s += c*c; }
    #pragma unroll
    for (int o = 32; o; o >>= 1) s += __shfl_xor(s, o, 64);
    if (l == 0) csq_s[w] = s * (1.f/512.f);
  }
  __syncthreads();

  // pass A: assignment (lane<->point, wave<->d-quarter)
  { const float* xp = X + (((size_t)(b*NSPK_ + n)*DIMS) + w*128)*TLEN + t;
    const float4* c4p = (const float4*)cent + w*128;
    float a0=0,a1=0,a2=0,a3=0;
    #pragma unroll 8
    for (int dq = 0; dq < 128; ++dq){
      float x = xp[(size_t)dq*TLEN];
      float4 c = c4p[dq];
      a0 += x*c.x; a1 += x*c.y; a2 += x*c.z; a3 += x*c.w;
    }
    red[w][0][l]=a0; red[w][1][l]=a1; red[w][2][l]=a2; red[w][3][l]=a3;
    __syncthreads();
    if (tid < PPB){
      float A0 = red[0][0][l]+red[1][0][l]+red[2][0][l]+red[3][0][l];
      float A1 = red[0][1][l]+red[1][1][l]+red[2][1][l]+red[3][1][l];
      float A2 = red[0][2][l]+red[1][2][l]+red[2][2][l]+red[3][2][l];
      float A3 = red[0][3][l]+red[1][3][l]+red[2][3][l]+red[3][3][l];
      float xs = fsq[P] * (1.f/512.f);
      float d0 = (xs + csq_s[0]) - 2.f*(A0*(1.f/512.f));
      float d1 = (xs + csq_s[1]) - 2.f*(A1*(1.f/512.f));
      float d2 = (xs + csq_s[2]) - 2.f*(A2*(1.f/512.f));
      float d3 = (xs + csq_s[3]) - 2.f*(A3*(1.f/512.f));
      int bi = 0; float bv = d0;            // first-min == np.argmin
      if (d1 < bv){ bv = d1; bi = 1; }
      if (d2 < bv){ bv = d2; bi = 2; }
      if (d3 < bv){ bv = d3; bi = 3; }
      ks[l] = bi;
      unsigned long long m0 = __ballot(bi==0), m1 = __ballot(bi==1);
      unsigned long long m2 = __ballot(bi==2), m3 = __ballot(bi==3);
      if (l == 0){
        pnum[blk*4+0] = __popcll(m0); pnum[blk*4+1] = __popcll(m1);
        pnum[blk*4+2] = __popcll(m2); pnum[blk*4+3] = __popcll(m3);
      }
    }
  }
  // pass B: per-cluster sums, d-chunked LDS tile (conflict-free, deterministic)
  const float* xbB = X + ((size_t)(b*NSPK_ + n)*DIMS)*TLEN + t;
  for (int dc = 0; dc < DIMS; dc += 64){
    #pragma unroll
    for (int rr = 0; rr < 16; ++rr){
      int r = w*16 + rr;
      tileb[r*TP + l] = xbB[(size_t)(dc + r)*TLEN];
    }
    __syncthreads();               // also makes ks visible on first chunk
    float acc0=0, acc1=0, acc2=0, acc3=0;
    #pragma unroll
    for (int pp = 0; pp < 16; ++pp){
      int pt = w*16 + pp;
      int kk = __builtin_amdgcn_readfirstlane(ks[pt]);   // wave-uniform
      float x = tileb[l*TP + pt];
      if (kk == 0) acc0 += x; else if (kk == 1) acc1 += x;
      else if (kk == 2) acc2 += x; else acc3 += x;
    }
    red[w][0][l]=acc0; red[w][1][l]=acc1; red[w][2][l]=acc2; red[w][3][l]=acc3;
    __syncthreads();
    { float s = red[0][w][l] + red[1][w][l] + red[2][w][l] + red[3][w][l];
      part[((size_t)blk*KC + w)*DIMS + dc + l] = s; }
  }
}

// ======== reduce partials -> centers. grid 256: blk = (bb*4+k)*8 + seg(64 d's)
__global__ __launch_bounds__(NTHR)
void k_reduce(const float* __restrict__ part, const int* __restrict__ pnum,
              float* __restrict__ C){
  const int blk = blockIdx.x, tid = threadIdx.x;
  const int seg = blk & 7, bk = blk >> 3;
  const int bb = bk >> 2, k = bk & 3;
  const int w = tid >> 6, l = tid & 63;
  __shared__ float red[4][64];
  __shared__ int ns[4];

  int v = 0;
  if (tid < BPB) v = pnum[(bb*BPB + tid)*4 + k];
  #pragma unroll
  for (int o = 32; o; o >>= 1) v += __shfl_xor(v, o, 64);
  if (l == 0) ns[w] = v;
  __syncthreads();
  float den = (float)(ns[0]+ns[1]+ns[2]+ns[3]) + 1e-8f;

  int jb = (BPB*w) >> 2, je = (BPB*(w+1)) >> 2;   // 0..31,31..62,62..93,93..125
  float s = 0.f;
  for (int j = jb; j < je; ++j)
    s += part[((size_t)(bb*BPB + j)*KC + k)*DIMS + seg*64 + l];
  red[w][l] = s;
  __syncthreads();
  if (tid < 64){
    float tsum = red[0][l] + red[1][l] + red[2][l] + red[3][l];
    C[bk*DIMS + seg*64 + l] = tsum / den;
  }
}

// ======================= host: threefry2x32 (JAX-compatible) =======================
static inline uint32_t rotl_(uint32_t x, int r){ return (x << r) | (x >> (32 - r)); }
static void tf2x32(uint32_t k0, uint32_t k1, uint32_t x0, uint32_t x1,
                   uint32_t* o0, uint32_t* o1){
  static const int R0[4] = {13,15,26,6}, R1[4] = {17,29,16,24};
  uint32_t ks[3] = { k0, k1, k0 ^ k1 ^ 0x1BD11BDAu };
  x0 += ks[0]; x1 += ks[1];
  for (int g = 0; g < 5; ++g){
    const int* rot = (g & 1) ? R1 : R0;
    for (int r = 0; r < 4; ++r){ x0 += x1; x1 = rotl_(x1, rot[r]); x1 ^= x0; }
    x0 += ks[(g+1)%3];
    x1 += ks[(g+2)%3] + (uint32_t)(g+1);
  }
  *o0 = x0; *o1 = x1;
}
static float tf_uniform_bits(uint32_t bits){
  uint32_t u = (bits >> 9) | 0x3f800000u;
  float f; memcpy(&f, &u, 4);
  return f - 1.0f;
}

extern "C" void kernel_launch(void* const* d_in, const int* in_sizes, int n_in,
                              void* d_out, int out_size, void* d_ws, size_t ws_size,
                              hipStream_t stream) {
  (void)in_sizes; (void)n_in; (void)out_size; (void)ws_size;
  const float* X = (const float*)d_in[0];
  float* centers = (float*)d_out;                 // (8,4,512)

  char* w = (char*)d_ws;
  float* fsq  = (float*)w;  w += (size_t)NBATCH*NPTS*4;            // 256 KB
  float* dmin = (float*)w;  w += (size_t)NBATCH*NPTS*4;            // 256 KB
  float* part = (float*)w;  w += (size_t)NBLK*KC*DIMS*4;           // 8.2 MB
  int*   pnum = (int*)w;    w += (size_t)NBLK*KC*4;                // 16 KB

  RArg ra;
  uint32_t k0 = 0u, k1 = 1u;
  for (int i = 0; i < 3; ++i){
#if THREEFRY_PARTITIONABLE
    uint32_t nk0, nk1, s0, s1;
    tf2x32(k0, k1, 0u, 0u, &nk0, &nk1);
    tf2x32(k0, k1, 0u, 1u, &s0, &s1);
    k0 = nk0; k1 = nk1;
    for (int bq = 0; bq < NBATCH; ++bq){
      uint32_t b1v, b2v; tf2x32(s0, s1, 0u, (uint32_t)bq, &b1v, &b2v);
      ra.r[i][bq] = tf_uniform_bits(b1v ^ b2v);
    }
#else
    uint32_t a0, b0, a1, b1;
    tf2x32(k0, k1, 0u, 2u, &a0, &b0);
    tf2x32(k0, k1, 1u, 3u, &a1, &b1);
    uint32_t s0 = b0, s1 = b1;
    k0 = a0; k1 = a1;
    uint32_t bits[8];
    for (int j = 0; j < 4; ++j){
      uint32_t c, d2; tf2x32(s0, s1, (uint32_t)j, (uint32_t)(j+4), &c, &d2);
      bits[j] = c; bits[j+4] = d2;
    }
    for (int bq = 0; bq < NBATCH; ++bq) ra.r[i][bq] = tf_uniform_bits(bits[bq]);
#endif
  }

  hipLaunchKernelGGL(k_prep, dim3(250), dim3(NTHR), 0, stream, X, centers, fsq);
  for (int i = 1; i < KC; ++i){
    hipLaunchKernelGGL(k_dist, dim3(NBLK), dim3(NTHR), 0, stream, X, centers, fsq, dmin);
    hipLaunchKernelGGL(k_select, dim3(NBATCH), dim3(NTHR), 0, stream, X, centers, dmin, ra, i);
  }
  for (int it = 0; it < MAXIT; ++it){
    hipLaunchKernelGGL(k_iter, dim3(NBLK), dim3(NTHR), 0, stream, X, centers, fsq, part, pnum);
    hipLaunchKernelGGL(k_reduce, dim3(256), dim3(NTHR), 0, stream, part, pnum, centers);
  }
}

// Round 5
// 6647.259 us; speedup vs baseline: 3.9378x; 1.0580x over previous
//
#include <hip/hip_runtime.h>
#include <stdint.h>
#include <string.h>

#define NBATCH 8
#define NSPK_  4
#define DIMS   512
#define TLEN   2000
#define KC     4
#define NPTS   8000            // points per batch
#define NBLK   1000            // Lloyd / dist grid
#define NTHR   256
#define PPB    64              // points per block
#define BPB    125             // blocks per batch
#define MAXIT  100
#define TS     33              // k_iter LDS tile row stride (d-major)

#define THREEFRY_PARTITIONABLE 1

struct RArg { float r[3][NBATCH]; };

// ---- exact replica of numpy pairwise_sum (umath loops), stride in elements ----
__device__ float np_pw(const float* a, int n, int st){
  #pragma clang fp contract(off)
  if (n < 8){
    float r = 0.f;
    for (int i = 0; i < n; ++i) r += a[(long)i*st];
    return r;
  }
  if (n <= 128){
    float r0=a[0], r1=a[st], r2=a[2*st], r3=a[3*st],
          r4=a[4*st], r5=a[5*st], r6=a[6*st], r7=a[7*st];
    int i = 8;
    for (; i < n - (n & 7); i += 8){
      r0 += a[(long)(i+0)*st]; r1 += a[(long)(i+1)*st];
      r2 += a[(long)(i+2)*st]; r3 += a[(long)(i+3)*st];
      r4 += a[(long)(i+4)*st]; r5 += a[(long)(i+5)*st];
      r6 += a[(long)(i+6)*st]; r7 += a[(long)(i+7)*st];
    }
    float res = ((r0 + r1) + (r2 + r3)) + ((r4 + r5) + (r6 + r7));
    for (; i < n; ++i) res += a[(long)i*st];
    return res;
  }
  int n2 = n/2; n2 -= (n2 & 7);
  return np_pw(a, n2, st) + np_pw(a + (long)n2*st, n - n2, st);
}
__device__ float np_pw_sq(const float* a, int n, int st){
  #pragma clang fp contract(off)
  if (n < 8){
    float r = 0.f;
    for (int i = 0; i < n; ++i){ float x = a[(long)i*st]; float s = x*x; r += s; }
    return r;
  }
  if (n <= 128){
    float x0=a[0],x1=a[st],x2=a[2*st],x3=a[3*st],
          x4=a[4*st],x5=a[5*st],x6=a[6*st],x7=a[7*st];
    float r0=x0*x0, r1=x1*x1, r2=x2*x2, r3=x3*x3,
          r4=x4*x4, r5=x5*x5, r6=x6*x6, r7=x7*x7;
    int i = 8;
    for (; i < n - (n & 7); i += 8){
      float y0=a[(long)(i+0)*st], y1=a[(long)(i+1)*st], y2=a[(long)(i+2)*st], y3=a[(long)(i+3)*st];
      float y4=a[(long)(i+4)*st], y5=a[(long)(i+5)*st], y6=a[(long)(i+6)*st], y7=a[(long)(i+7)*st];
      r0 += y0*y0; r1 += y1*y1; r2 += y2*y2; r3 += y3*y3;
      r4 += y4*y4; r5 += y5*y5; r6 += y6*y6; r7 += y7*y7;
    }
    float res = ((r0 + r1) + (r2 + r3)) + ((r4 + r5) + (r6 + r7));
    for (; i < n; ++i){ float x = a[(long)i*st]; float s = x*x; res += s; }
    return res;
  }
  int n2 = n/2; n2 -= (n2 & 7);
  return np_pw_sq(a, n2, st) + np_pw_sq(a + (long)n2*st, n - n2, st);
}

// ======== phase 0: fsq (np-exact), center row 0 = feature[:,0,:,0], rows 1..3 = 0
__global__ __launch_bounds__(NTHR)
void k_prep(const float* __restrict__ X, float* __restrict__ C, float* __restrict__ fsq){
  const int blk = blockIdx.x, tid = threadIdx.x;
  int Pf = blk*NTHR + tid;                 // 250*256 = 64000
  int bf = Pf / NPTS, gf = Pf - bf*NPTS;
  int nf = gf / TLEN, tf = gf - nf*TLEN;
  fsq[Pf] = np_pw_sq(X + ((size_t)(bf*NSPK_ + nf)*DIMS)*TLEN + tf, DIMS, TLEN);
  if (blk < NBATCH){
    for (int d = tid; d < DIMS; d += NTHR)
      C[blk*KC*DIMS + d] = X[((size_t)(blk*NSPK_)*DIMS + d)*TLEN];
  } else if (blk < 2*NBATCH){
    int bb = blk - NBATCH;
    for (int e = tid; e < 3*DIMS; e += NTHR) C[bb*KC*DIMS + DIMS + e] = 0.f;
  }
}

// ======== init dist: dmin over all 4 rows (zero rows give fsq == reference :i+1 slice)
__global__ __launch_bounds__(NTHR)
void k_dist(const float* __restrict__ X, const float* __restrict__ C,
            const float* __restrict__ fsq, float* __restrict__ dmin){
  const int blk = blockIdx.x, tid = threadIdx.x;
  const int w = tid >> 6, l = tid & 63;
  const int b = blk / BPB;
  const int P = blk*PPB + l;
  const int g = P - b*NPTS;
  const int n = g / TLEN, t = g - n*TLEN;

  __shared__ __align__(16) float cent[DIMS*KC];
  __shared__ float red[4][KC][PPB];
  __shared__ float csq_s[KC];

  const float* Cb = C + b*KC*DIMS;
  #pragma unroll
  for (int j = 0; j < 8; ++j){
    int e = tid*8 + j;
    cent[e] = Cb[(e&3)*DIMS + (e>>2)];
  }
  { const float* ck = Cb + w*DIMS + l*8;
    float s = 0.f;
    #pragma unroll
    for (int j = 0; j < 8; ++j){ float c = ck[j]; s += c*c; }
    #pragma unroll
    for (int o = 32; o; o >>= 1) s += __shfl_xor(s, o, 64);
    if (l == 0) csq_s[w] = s;
  }
  __syncthreads();

  const float* xp = X + (((size_t)(b*NSPK_ + n)*DIMS) + w*128)*TLEN + t;
  const float4* c4p = (const float4*)cent + w*128;
  float a0=0,a1=0,a2=0,a3=0;
  #pragma unroll 8
  for (int dq = 0; dq < 128; ++dq){
    float x = xp[(size_t)dq*TLEN];
    float4 c = c4p[dq];
    a0 += x*c.x; a1 += x*c.y; a2 += x*c.z; a3 += x*c.w;
  }
  red[w][0][l]=a0; red[w][1][l]=a1; red[w][2][l]=a2; red[w][3][l]=a3;
  __syncthreads();
  if (tid < PPB){
    float A0 = red[0][0][l]+red[1][0][l]+red[2][0][l]+red[3][0][l];
    float A1 = red[0][1][l]+red[1][1][l]+red[2][1][l]+red[3][1][l];
    float A2 = red[0][2][l]+red[1][2][l]+red[2][2][l]+red[3][2][l];
    float A3 = red[0][3][l]+red[1][3][l]+red[2][3][l]+red[3][3][l];
    float fs = fsq[P];
    float dm = (fs + csq_s[0]) - 2.f*A0;
    dm = fminf(dm, (fs + csq_s[1]) - 2.f*A1);
    dm = fminf(dm, (fs + csq_s[2]) - 2.f*A2);
    dm = fminf(dm, (fs + csq_s[3]) - 2.f*A3);
    dmin[P] = dm;
  }
}

// ======== selection (np-exact): grid 8, one block per batch; writes center row i
__global__ __launch_bounds__(NTHR)
void k_select(const float* __restrict__ X, float* __restrict__ C,
              const float* __restrict__ dmin, RArg ra, int i){
  const int bs = blockIdx.x, tid = threadIdx.x;
  __shared__ __align__(16) float sbuf[TLEN];
  __shared__ float fsh[4];
  __shared__ int   ish[1];
  float rT = ra.r[i-1][bs];

  // total = exact np pairwise tree: 8000 = ((2000+2000)+(2000+2000))
  for (int c = 0; c < 4; ++c){
    for (int e = tid; e < TLEN; e += NTHR) sbuf[e] = dmin[bs*NPTS + c*TLEN + e];
    __syncthreads();
    if (tid == 0) fsh[c] = np_pw(sbuf, TLEN, 1);
    __syncthreads();
  }
  float tot = (fsh[0] + fsh[1]) + (fsh[2] + fsh[3]);

  // q = d/tot (IEEE div, parallel) then sequential fp32 cumsum count (np semantics),
  // batched register loads so the only serial cost is the v_add_f32 chain.
  float run = 0.f; int cnt = 0;
  for (int c = 0; c < 4; ++c){
    for (int e = tid; e < TLEN; e += NTHR) sbuf[e] = dmin[bs*NPTS + c*TLEN + e] / tot;
    __syncthreads();
    if (tid == 0){
      #pragma clang fp contract(off)
      for (int j = 0; j < TLEN; j += 16){
        float vv[16];
        #pragma unroll
        for (int u = 0; u < 16; ++u) vv[u] = sbuf[j + u];
        #pragma unroll
        for (int u = 0; u < 16; ++u){
          run = run + vv[u];            // exact sequential fp32 cumsum
          if (run <= rT) ++cnt;
        }
      }
    }
    __syncthreads();
  }
  if (tid == 0) ish[0] = cnt - 1;
  __syncthreads();
  int sel = ish[0];
  for (int d = tid; d < DIMS; d += NTHR){
    float v = 0.f;
    if (sel >= 0){
      int ns = sel / TLEN, ts = sel - ns*TLEN;
      v = X[((size_t)(bs*NSPK_ + ns)*DIMS + d)*TLEN + ts];
    }
    C[(bs*KC + i)*DIMS + d] = v;
  }
}

// ======== Lloyd iteration: single X read — stage 32-pt tile in LDS, assign, sum
__global__ __launch_bounds__(NTHR, 2)
void k_iter(const float* __restrict__ X, const float* __restrict__ C,
            const float* __restrict__ fsq, float* __restrict__ part,
            int* __restrict__ pnum){
  const int blk = blockIdx.x, tid = threadIdx.x;
  const int p = tid & 31, dg = tid >> 5;        // point-slot (32), d-group (8x64)
  const int b = blk / BPB;
  const int g0 = (blk - b*BPB)*PPB;             // first point of block within batch

  __shared__ __align__(16) float cent[DIMS*KC];  // 8 KB  [d*4+k]
  __shared__ float tile[DIMS*TS];                // 67.6 KB [d*33 + p]
  __shared__ float red[8][KC][32];               // 4 KB
  __shared__ int   ks[32];
  __shared__ float csq_s[KC];
  __shared__ int   cntk[KC];

  // stage centers + csq (mean scale 1/512)
  const float* Cb = C + b*KC*DIMS;
  #pragma unroll
  for (int j = 0; j < 8; ++j){
    int e = tid*8 + j;
    cent[e] = Cb[(e&3)*DIMS + (e>>2)];
  }
  { const int w = tid >> 6, l = tid & 63;
    const float* ck = Cb + w*DIMS + l*8;
    float s = 0.f;
    #pragma unroll
    for (int j = 0; j < 8; ++j){ float c = ck[j]; s += c*c; }
    #pragma unroll
    for (int o = 32; o; o >>= 1) s += __shfl_xor(s, o, 64);
    if (l == 0) csq_s[w] = s * (1.f/512.f);
  }
  if (tid < KC) cntk[tid] = 0;
  __syncthreads();

  // pass-B register accumulators: d-slots (tid, tid+256) x 4 clusters
  float s00=0,s01=0,s02=0,s03=0, s10=0,s11=0,s12=0,s13=0;
  const int d0 = tid, d1 = tid + 256;

  for (int h = 0; h < 2; ++h){
    // --- stage tile + dot partials (thread = (p, dg); 64 d's each)
    const int g = g0 + h*32 + p;
    const int n = g / TLEN, t = g - n*TLEN;
    const float* xp = X + (((size_t)(b*NSPK_ + n)*DIMS) + dg*64)*TLEN + t;
    float a0=0,a1=0,a2=0,a3=0;
    #pragma unroll 8
    for (int dd = 0; dd < 64; ++dd){
      float x = xp[(size_t)dd*TLEN];
      int d = dg*64 + dd;
      tile[d*TS + p] = x;
      float4 c = ((const float4*)cent)[d];
      a0 += x*c.x; a1 += x*c.y; a2 += x*c.z; a3 += x*c.w;
    }
    red[dg][0][p]=a0; red[dg][1][p]=a1; red[dg][2][p]=a2; red[dg][3][p]=a3;
    __syncthreads();
    // --- assignment for these 32 points (wave 0, lane = point)
    if (tid < 32){
      float A0=0,A1=0,A2=0,A3=0;
      #pragma unroll
      for (int q = 0; q < 8; ++q){
        A0 += red[q][0][tid]; A1 += red[q][1][tid];
        A2 += red[q][2][tid]; A3 += red[q][3][tid];
      }
      float xs = fsq[b*NPTS + g0 + h*32 + tid] * (1.f/512.f);
      float e0 = (xs + csq_s[0]) - 2.f*(A0*(1.f/512.f));
      float e1 = (xs + csq_s[1]) - 2.f*(A1*(1.f/512.f));
      float e2 = (xs + csq_s[2]) - 2.f*(A2*(1.f/512.f));
      float e3 = (xs + csq_s[3]) - 2.f*(A3*(1.f/512.f));
      int bi = 0; float bv = e0;            // first-min == np.argmin
      if (e1 < bv){ bv = e1; bi = 1; }
      if (e2 < bv){ bv = e2; bi = 2; }
      if (e3 < bv){ bv = e3; bi = 3; }
      ks[tid] = bi;
      unsigned long long m0 = __ballot(bi==0), m1 = __ballot(bi==1);
      unsigned long long m2 = __ballot(bi==2), m3 = __ballot(bi==3);
      if (tid == 0){
        cntk[0] += __popcll(m0); cntk[1] += __popcll(m1);
        cntk[2] += __popcll(m2); cntk[3] += __popcll(m3);
      }
    }
    __syncthreads();
    // --- accumulate cluster sums for this half (thread <-> d, wave-uniform k)
    #pragma unroll 4
    for (int p2 = 0; p2 < 32; ++p2){
      int kk = __builtin_amdgcn_readfirstlane(ks[p2]);   // wave-uniform scalar
      float x0 = tile[d0*TS + p2];
      float x1 = tile[d1*TS + p2];
      if (kk == 0){ s00 += x0; s10 += x1; }
      else if (kk == 1){ s01 += x0; s11 += x1; }
      else if (kk == 2){ s02 += x0; s12 += x1; }
      else { s03 += x0; s13 += x1; }
    }
    __syncthreads();   // tile reused next half
  }

  if (tid < KC) pnum[blk*4 + tid] = cntk[tid];
  // partials: part[(blk*4 + k)*512 + d], coalesced across threads
  part[((size_t)blk*KC + 0)*DIMS + d0] = s00;
  part[((size_t)blk*KC + 1)*DIMS + d0] = s01;
  part[((size_t)blk*KC + 2)*DIMS + d0] = s02;
  part[((size_t)blk*KC + 3)*DIMS + d0] = s03;
  part[((size_t)blk*KC + 0)*DIMS + d1] = s10;
  part[((size_t)blk*KC + 1)*DIMS + d1] = s11;
  part[((size_t)blk*KC + 2)*DIMS + d1] = s12;
  part[((size_t)blk*KC + 3)*DIMS + d1] = s13;
}

// ======== reduce partials -> centers. grid 256: blk = (bb*4+k)*8 + seg(64 d's)
__global__ __launch_bounds__(NTHR)
void k_reduce(const float* __restrict__ part, const int* __restrict__ pnum,
              float* __restrict__ C){
  const int blk = blockIdx.x, tid = threadIdx.x;
  const int seg = blk & 7, bk = blk >> 3;
  const int bb = bk >> 2, k = bk & 3;
  const int w = tid >> 6, l = tid & 63;
  __shared__ float red[4][64];
  __shared__ int ns[4];

  int v = 0;
  if (tid < BPB) v = pnum[(bb*BPB + tid)*4 + k];
  #pragma unroll
  for (int o = 32; o; o >>= 1) v += __shfl_xor(v, o, 64);
  if (l == 0) ns[w] = v;
  __syncthreads();
  float den = (float)(ns[0]+ns[1]+ns[2]+ns[3]) + 1e-8f;

  int jb = (BPB*w) >> 2, je = (BPB*(w+1)) >> 2;   // fixed quarters of 125
  float s = 0.f;
  for (int j = jb; j < je; ++j)
    s += part[((size_t)(bb*BPB + j)*KC + k)*DIMS + seg*64 + l];
  red[w][l] = s;
  __syncthreads();
  if (tid < 64){
    float tsum = red[0][l] + red[1][l] + red[2][l] + red[3][l];
    C[bk*DIMS + seg*64 + l] = tsum / den;
  }
}

// ======================= host: threefry2x32 (JAX-compatible) =======================
static inline uint32_t rotl_(uint32_t x, int r){ return (x << r) | (x >> (32 - r)); }
static void tf2x32(uint32_t k0, uint32_t k1, uint32_t x0, uint32_t x1,
                   uint32_t* o0, uint32_t* o1){
  static const int R0[4] = {13,15,26,6}, R1[4] = {17,29,16,24};
  uint32_t ks[3] = { k0, k1, k0 ^ k1 ^ 0x1BD11BDAu };
  x0 += ks[0]; x1 += ks[1];
  for (int g = 0; g < 5; ++g){
    const int* rot = (g & 1) ? R1 : R0;
    for (int r = 0; r < 4; ++r){ x0 += x1; x1 = rotl_(x1, rot[r]); x1 ^= x0; }
    x0 += ks[(g+1)%3];
    x1 += ks[(g+2)%3] + (uint32_t)(g+1);
  }
  *o0 = x0; *o1 = x1;
}
static float tf_uniform_bits(uint32_t bits){
  uint32_t u = (bits >> 9) | 0x3f800000u;
  float f; memcpy(&f, &u, 4);
  return f - 1.0f;
}

extern "C" void kernel_launch(void* const* d_in, const int* in_sizes, int n_in,
                              void* d_out, int out_size, void* d_ws, size_t ws_size,
                              hipStream_t stream) {
  (void)in_sizes; (void)n_in; (void)out_size; (void)ws_size;
  const float* X = (const float*)d_in[0];
  float* centers = (float*)d_out;                 // (8,4,512)

  char* w = (char*)d_ws;
  float* fsq  = (float*)w;  w += (size_t)NBATCH*NPTS*4;            // 256 KB
  float* dmin = (float*)w;  w += (size_t)NBATCH*NPTS*4;            // 256 KB
  float* part = (float*)w;  w += (size_t)NBLK*KC*DIMS*4;           // 8.2 MB
  int*   pnum = (int*)w;    w += (size_t)NBLK*KC*4;                // 16 KB

  RArg ra;
  uint32_t k0 = 0u, k1 = 1u;
  for (int i = 0; i < 3; ++i){
#if THREEFRY_PARTITIONABLE
    uint32_t nk0, nk1, s0, s1;
    tf2x32(k0, k1, 0u, 0u, &nk0, &nk1);
    tf2x32(k0, k1, 0u, 1u, &s0, &s1);
    k0 = nk0; k1 = nk1;
    for (int bq = 0; bq < NBATCH; ++bq){
      uint32_t b1v, b2v; tf2x32(s0, s1, 0u, (uint32_t)bq, &b1v, &b2v);
      ra.r[i][bq] = tf_uniform_bits(b1v ^ b2v);
    }
#else
    uint32_t a0, b0, a1, b1;
    tf2x32(k0, k1, 0u, 2u, &a0, &b0);
    tf2x32(k0, k1, 1u, 3u, &a1, &b1);
    uint32_t s0 = b0, s1 = b1;
    k0 = a0; k1 = a1;
    uint32_t bits[8];
    for (int j = 0; j < 4; ++j){
      uint32_t c, d2; tf2x32(s0, s1, (uint32_t)j, (uint32_t)(j+4), &c, &d2);
      bits[j] = c; bits[j+4] = d2;
    }
    for (int bq = 0; bq < NBATCH; ++bq) ra.r[i][bq] = tf_uniform_bits(bits[bq]);
#endif
  }

  hipLaunchKernelGGL(k_prep, dim3(250), dim3(NTHR), 0, stream, X, centers, fsq);
  for (int i = 1; i < KC; ++i){
    hipLaunchKernelGGL(k_dist, dim3(NBLK), dim3(NTHR), 0, stream, X, centers, fsq, dmin);
    hipLaunchKernelGGL(k_select, dim3(NBATCH), dim3(NTHR), 0, stream, X, centers, dmin, ra, i);
  }
  for (int it = 0; it < MAXIT; ++it){
    hipLaunchKernelGGL(k_iter, dim3(NBLK), dim3(NTHR), 0, stream, X, centers, fsq, part, pnum);
    hipLaunchKernelGGL(k_reduce, dim3(256), dim3(NTHR), 0, stream, part, pnum, centers);
  }
}